// Round 1
// 413.237 us; speedup vs baseline: 1.2117x; 1.2117x over previous
//
#include <hip/hip_runtime.h>
#include <hip/hip_bf16.h>

typedef short bf16x4 __attribute__((ext_vector_type(4)));
typedef short bf16x8 __attribute__((ext_vector_type(8)));
typedef float f32x4  __attribute__((ext_vector_type(4)));

__device__ inline unsigned short f2us(float f) {
    __hip_bfloat16 h = __float2bfloat16(f);
    return *(unsigned short*)&h;
}
__device__ inline float us2f(unsigned short u) {
    union { unsigned int i; float f; } c; c.i = ((unsigned int)u) << 16; return c.f;
}
__device__ inline float tanh_fast(float x) {
    float xs = fminf(fmaxf(x, -20.f), 20.f);
    float t = __expf(2.f * xs);
    return 1.f - 2.f / (t + 1.f);
}

// async global->LDS, 16 B per lane; LDS dest = wave-uniform base + lane*16
__device__ inline void gload_lds16(const void* g, void* l) {
    __builtin_amdgcn_global_load_lds(
        (const __attribute__((address_space(1))) void*)g,
        (__attribute__((address_space(3))) void*)l,
        16, 0, 0);
}

// ---------------- prep: x fp32 NCHW -> bf16 channel-last [n][h][w][c] ----------
__global__ __launch_bounds__(256) void prep_x(const float* __restrict__ x,
                                              unsigned short* __restrict__ xcl)
{
    __shared__ unsigned short t2[128 * 68];
    int bid = blockIdx.x;           // n*128 + h
    int n = bid >> 7, h = bid & 127;
    const float* xp = x + (size_t)n * 64 * 16384 + h * 128;
    int t = threadIdx.x;
    for (int i = t; i < 8192; i += 256) {
        int ci = i >> 7, w = i & 127;
        t2[w * 68 + ci] = f2us(xp[(size_t)ci * 16384 + w]);
    }
    __syncthreads();
    unsigned short* op = xcl + ((size_t)(n * 16384 + h * 128)) * 64;
    for (int i = t; i < 1024; i += 256) {
        int w = i >> 3, c8 = i & 7;
        union { bf16x4 v[2]; uint4 q; } u;
        u.v[0] = *(bf16x4*)&t2[w * 68 + c8 * 8];
        u.v[1] = *(bf16x4*)&t2[w * 68 + c8 * 8 + 4];
        *(uint4*)(op + w * 64 + c8 * 8) = u.q;
    }
}

// ---------------- prep: weights -> MFMA B-fragment order, bf16 ------------------
// Layer l: 36864 ushorts at Wf + l*36864.
// idx within layer: ((((t*2+hh)*4+nb)*64 + lane)*8 + j)
// element: ci = hh*32 + (lane>>4)*8 + j ; co = nb*16 + (lane&15) ; W[co][ci][tap]
__global__ void prep_wf(const float* __restrict__ w0, const float* __restrict__ wm,
                        const float* __restrict__ wl, unsigned short* __restrict__ Wf)
{
    int idx = blockIdx.x * 256 + threadIdx.x;
    if (idx >= 258048) return;
    int l = idx / 36864, r = idx - l * 36864;
    int tp = r >> 12, r2 = r & 4095;
    int hh = r2 >> 11, nb = (r2 >> 9) & 3, ln = (r2 >> 3) & 63, j = r2 & 7;
    int ci = hh * 32 + (ln >> 4) * 8 + j;
    int co = nb * 16 + (ln & 15);
    float val = 0.f;
    if (l < 6) {
        const float* src = (l == 0) ? w0 : (wm + (size_t)(l - 1) * 36864);
        val = src[(co * 64 + ci) * 9 + tp];
    } else if (co < 36) {
        val = wl[(co * 64 + ci) * 9 + tp];
    }
    Wf[idx] = f2us(val);
}

// ---------------- prep: fold bias + BN into per-channel A (scale), B (shift) ----
__global__ void prep_ab(const float* b0, const float* g0, const float* be0,
                        const float* m0, const float* v0,
                        const float* bm, const float* gm, const float* bem,
                        const float* mm, const float* vm,
                        const float* bl, const float* gl, const float* bel,
                        const float* ml, const float* vl,
                        float* __restrict__ Af, float* __restrict__ Bf)
{
    int idx = blockIdx.x * 256 + threadIdx.x;
    if (idx >= 448) return;
    int l = idx >> 6, c = idx & 63;
    float b, g, be, m, v;
    if (l == 0) {
        b = b0[c]; g = g0[c]; be = be0[c]; m = m0[c]; v = v0[c];
    } else if (l < 6) {
        int o = (l - 1) * 64 + c;
        b = bm[o]; g = gm[o]; be = bem[o]; m = mm[o]; v = vm[o];
    } else {
        if (c >= 36) { Af[idx] = 0.f; Bf[idx] = 0.f; return; }
        b = bl[c]; g = gl[c]; be = bel[c]; m = ml[c]; v = vl[c];
    }
    float s = g / sqrtf(v + 1e-5f);
    Af[idx] = s;
    Bf[idx] = (b - m) * s + be;
}

// ---------------- conv 3x3 + BN + tanh via MFMA implicit GEMM -------------------
// grid (4,8,8) = (w/32, h/16, n), block 512 = 8 waves, 1 block/CU (LDS 152064 B).
// Tile: 32w x 16h output px; halo 34w x 18h, channel-last bf16, row stride 128 B.
// LDS tile layout: px p = ty*34+tx occupies bytes [p*128, p*128+128); 16-B chunk j
// of px p stored at physical chunk j ^ (p&7)  (T2 XOR swizzle, via pre-swizzled
// global source so global_load_lds' linear dest works; read applies same XOR).
// Weights (73728 B, prep_wf layout) staged once per block at LDS_W_OFF.
// Wave wv: output rows wv*2, wv*2+1 (2 rh) x 2 w-halves x all 64 co (4 nb).
#define LDS_W_OFF 78336
__global__ __launch_bounds__(512, 2)
void conv_mfma(const unsigned short* __restrict__ src,
               const unsigned short* __restrict__ Wf,
               const float* __restrict__ A, const float* __restrict__ B,
               unsigned short* __restrict__ dst)
{
    __shared__ __align__(16) unsigned char smem[152064];   // 78336 tile + 73728 W
    const int n = blockIdx.z;
    const int h0 = blockIdx.y * 16, w0 = blockIdx.x * 32;
    const int t = threadIdx.x;
    const int ln = t & 63, wv = t >> 6;
    const int xln = ln & 15, qd = ln >> 4;
    const size_t ibase = (size_t)n * 16384 * 64;

    // zero tile region (halo OOB stays 0; masked DMA lanes skip their write)
    {
        uint4 z = make_uint4(0u, 0u, 0u, 0u);
        for (int c = t; c < 4896; c += 512)
            *(uint4*)(smem + (size_t)c * 16) = z;
    }
    __syncthreads();

    // stage input tile: 612 px * 8 chunks = 4896 chunks, 77 wave-insts
    const unsigned short* srcn = src + ibase;
    for (int i = wv; i < 77; i += 8) {
        int g = i * 64 + ln;
        int p = g >> 3, jj = g & 7;
        int ty = (p * 1928) >> 16;          // p/34, exact for p<612
        int tx = p - ty * 34;
        int gy = h0 + ty - 1, gx = w0 + tx - 1;
        int js = jj ^ (p & 7);              // inverse-swizzled source chunk
        bool ok = (g < 4896) & ((unsigned)gy < 128u) & ((unsigned)gx < 128u);
        const unsigned short* gsrc = srcn + (ptrdiff_t)(gy * 128 + gx) * 64 + js * 8;
        if (ok) gload_lds16(gsrc, smem + (size_t)i * 1024);
    }
    // stage weights: 73728 B = 4608 chunks, 72 wave-insts, linear
    for (int i = wv; i < 72; i += 8) {
        const unsigned short* gsrc = Wf + ((size_t)(i * 64 + ln)) * 8;
        gload_lds16(gsrc, smem + LDS_W_OFF + (size_t)i * 1024);
    }
    __syncthreads();   // drains vmcnt(0): all DMA landed

    f32x4 acc[2][2][4];     // [rh][half][nb]
#pragma unroll
    for (int rh = 0; rh < 2; ++rh)
#pragma unroll
        for (int hf = 0; hf < 2; ++hf)
#pragma unroll
            for (int nb = 0; nb < 4; ++nb)
                acc[rh][hf][nb] = (f32x4){0.f, 0.f, 0.f, 0.f};

    const int rbase = wv * 2;
#pragma unroll
    for (int tp = 0; tp < 9; ++tp) {
        const int ky = tp / 3, kx = tp % 3;
        bf16x8 b[2][4];
#pragma unroll
        for (int hh = 0; hh < 2; ++hh)
#pragma unroll
            for (int nb = 0; nb < 4; ++nb)
                b[hh][nb] = *(const bf16x8*)(smem + LDS_W_OFF +
                    (((((tp * 2 + hh) * 4 + nb) * 64) + ln) << 4));
#pragma unroll
        for (int rh = 0; rh < 2; ++rh) {
#pragma unroll
            for (int hf = 0; hf < 2; ++hf) {
                const int p = (rbase + rh + ky) * 34 + hf * 16 + xln + kx;
                const int pb = p * 128, sw = (p & 7) << 4;
#pragma unroll
                for (int hh = 0; hh < 2; ++hh) {
                    bf16x8 a = *(const bf16x8*)(smem + pb +
                                                (((qd + 4 * hh) << 4) ^ sw));
#pragma unroll
                    for (int nb = 0; nb < 4; ++nb)
                        acc[rh][hf][nb] = __builtin_amdgcn_mfma_f32_16x16x32_bf16(
                            a, b[hh][nb], acc[rh][hf][nb], 0, 0, 0);
                }
            }
        }
    }

    // epilogue: BN + tanh -> bf16 channel-last
#pragma unroll
    for (int nb = 0; nb < 4; ++nb) {
        const int co = nb * 16 + xln;
        const float As = A[co], Bs = B[co];
#pragma unroll
        for (int rh = 0; rh < 2; ++rh) {
            const int gy = h0 + rbase + rh;
            unsigned short* dp = dst + ibase + (size_t)(gy * 128) * 64;
#pragma unroll
            for (int hf = 0; hf < 2; ++hf) {
#pragma unroll
                for (int r = 0; r < 4; ++r) {
                    const int gx = w0 + hf * 16 + qd * 4 + r;
                    float y = tanh_fast(fmaf(acc[rh][hf][nb][r], As, Bs));
                    dp[(size_t)gx * 64 + co] = f2us(y);
                }
            }
        }
    }
}

// ---------------- dynamic conv: coef = h7·bases; out = coef · patches(x) -------
// grid (4,16,8), block 256 = 8x32 px. h7 is bf16 channel-last (64-stride, 36 used).
__global__ __launch_bounds__(256)
void dyn_conv(const float* __restrict__ x, const unsigned short* __restrict__ h7,
              const float* __restrict__ bases, float* __restrict__ out)
{
    __shared__ float tile[32 * 10 * 34];
    const int n = blockIdx.z;
    const int h0 = blockIdx.y * 8, w0 = blockIdx.x * 32;
    const float* xp = x + (size_t)n * 64 * 16384;
    const int t = threadIdx.x;
    const int tw = t & 31, th = t >> 5;
    const int h = h0 + th, w = w0 + tw;

    float bs[54];
#pragma unroll
    for (int i = 0; i < 54; ++i) bs[i] = bases[i];    // [k][l], block-uniform

    // load 36 bf16 features (contiguous) via 5 x uint4
    union { uint4 q[5]; unsigned short s[40]; } hv;
    const unsigned short* hp = h7 + (size_t)(n * 16384 + h * 128 + w) * 64;
#pragma unroll
    for (int i = 0; i < 5; ++i) hv.q[i] = ((const uint4*)hp)[i];

    float coef[54];   // [m][l]
#pragma unroll
    for (int i = 0; i < 54; ++i) coef[i] = 0.f;
#pragma unroll
    for (int m = 0; m < 6; ++m)
#pragma unroll
        for (int k = 0; k < 6; ++k) {
            float f = us2f(hv.s[m * 6 + k]);
#pragma unroll
            for (int l = 0; l < 9; ++l)
                coef[m * 9 + l] = fmaf(f, bs[k * 9 + l], coef[m * 9 + l]);
        }

    float* op = out + (size_t)n * 384 * 16384 + h * 128 + w;

    for (int half = 0; half < 2; ++half) {
        if (half) __syncthreads();
        for (int idx = t; idx < 32 * 340; idx += 256) {
            int ci = idx / 340, r = idx % 340, y = r / 34, xw = r % 34;
            int gy = h0 + y - 1, gx = w0 + xw - 1;
            float v = 0.f;
            if ((unsigned)gy < 128u && (unsigned)gx < 128u)
                v = xp[(size_t)(half * 32 + ci) * 16384 + gy * 128 + gx];
            tile[idx] = v;
        }
        __syncthreads();

#pragma unroll 1
        for (int c = 0; c < 32; ++c) {
            float xv[9];
#pragma unroll
            for (int ky = 0; ky < 3; ++ky)
#pragma unroll
                for (int kx = 0; kx < 3; ++kx)
                    xv[ky * 3 + kx] = tile[c * 340 + (th + ky) * 34 + (tw + kx)];
            int cg = half * 32 + c;
#pragma unroll
            for (int m = 0; m < 6; ++m) {
                float s = 0.f;
#pragma unroll
                for (int l = 0; l < 9; ++l) s = fmaf(coef[m * 9 + l], xv[l], s);
                op[(size_t)(cg * 6 + m) * 16384] = s;
            }
        }
    }
}

// ---------------- launch -------------------------------------------------------
extern "C" void kernel_launch(void* const* d_in, const int* in_sizes, int n_in,
                              void* d_out, int out_size, void* d_ws, size_t ws_size,
                              hipStream_t stream)
{
    const float* x   = (const float*)d_in[0];
    const float* w0  = (const float*)d_in[1];
    const float* b0  = (const float*)d_in[2];
    const float* g0  = (const float*)d_in[3];
    const float* be0 = (const float*)d_in[4];
    const float* m0  = (const float*)d_in[5];
    const float* v0  = (const float*)d_in[6];
    const float* wm  = (const float*)d_in[7];
    const float* bm  = (const float*)d_in[8];
    const float* gm  = (const float*)d_in[9];
    const float* bem = (const float*)d_in[10];
    const float* mm  = (const float*)d_in[11];
    const float* vm  = (const float*)d_in[12];
    const float* wl  = (const float*)d_in[13];
    const float* bl  = (const float*)d_in[14];
    const float* gl  = (const float*)d_in[15];
    const float* bel = (const float*)d_in[16];
    const float* ml  = (const float*)d_in[17];
    const float* vl  = (const float*)d_in[18];
    const float* bas = (const float*)d_in[19];

    unsigned short* Wfb = (unsigned short*)d_ws;                    // 516096 B
    float* Af  = (float*)((char*)d_ws + 524288);                    // 448 floats
    float* Bf  = Af + 448;
    unsigned short* xcl  = (unsigned short*)((char*)d_ws + (size_t)(2  << 20));
    unsigned short* bufA = (unsigned short*)((char*)d_ws + (size_t)(2  << 20) + 16777216);
    unsigned short* bufB = (unsigned short*)((char*)d_ws + (size_t)(2  << 20) + 2 * 16777216);

    prep_x<<<1024, 256, 0, stream>>>(x, xcl);
    prep_wf<<<1008, 256, 0, stream>>>(w0, wm, wl, Wfb);
    prep_ab<<<2, 256, 0, stream>>>(b0, g0, be0, m0, v0,
                                   bm, gm, bem, mm, vm,
                                   bl, gl, bel, ml, vl, Af, Bf);

    dim3 cg(4, 8, 8);
    conv_mfma<<<cg, 512, 0, stream>>>(xcl,  Wfb + 0 * 36864, Af + 0,   Bf + 0,   bufA);
    conv_mfma<<<cg, 512, 0, stream>>>(bufA, Wfb + 1 * 36864, Af + 64,  Bf + 64,  bufB);
    conv_mfma<<<cg, 512, 0, stream>>>(bufB, Wfb + 2 * 36864, Af + 128, Bf + 128, bufA);
    conv_mfma<<<cg, 512, 0, stream>>>(bufA, Wfb + 3 * 36864, Af + 192, Bf + 192, bufB);
    conv_mfma<<<cg, 512, 0, stream>>>(bufB, Wfb + 4 * 36864, Af + 256, Bf + 256, bufA);
    conv_mfma<<<cg, 512, 0, stream>>>(bufA, Wfb + 5 * 36864, Af + 320, Bf + 320, bufB);
    conv_mfma<<<cg, 512, 0, stream>>>(bufB, Wfb + 6 * 36864, Af + 384, Bf + 384, bufA);

    dim3 dg(4, 16, 8);
    dyn_conv<<<dg, 256, 0, stream>>>(x, bufA, bas, (float*)d_out);
}

// Round 2
// 403.692 us; speedup vs baseline: 1.2404x; 1.0236x over previous
//
#include <hip/hip_runtime.h>
#include <hip/hip_bf16.h>

typedef short bf16x4 __attribute__((ext_vector_type(4)));
typedef short bf16x8 __attribute__((ext_vector_type(8)));
typedef float f32x4  __attribute__((ext_vector_type(4)));

__device__ inline unsigned short f2us(float f) {
    __hip_bfloat16 h = __float2bfloat16(f);
    return *(unsigned short*)&h;
}
__device__ inline float us2f(unsigned short u) {
    union { unsigned int i; float f; } c; c.i = ((unsigned int)u) << 16; return c.f;
}
__device__ inline float tanh_fast(float x) {
    float xs = fminf(fmaxf(x, -20.f), 20.f);
    float t = __expf(2.f * xs);
    return 1.f - 2.f / (t + 1.f);
}

// async global->LDS, 16 B per lane; LDS dest = wave-uniform base + lane*16
__device__ inline void gload_lds16(const void* g, void* l) {
    __builtin_amdgcn_global_load_lds(
        (const __attribute__((address_space(1))) void*)g,
        (__attribute__((address_space(3))) void*)l,
        16, 0, 0);
}

// ---------------- fused prep: x->bf16 CL | weights->B-frag | BN fold | zeropage -
// blocks 0..1023: prep_x ; 1024..2031: prep_wf ; 2032..2033: prep_ab (+zeropage)
// Weight fragment: idx = ((((tp*2+hh)*4+nb)*64 + ln)*8 + j)
//   ci = hh*32 + (ln>>4)*8 + j ; real co = (ln&15)*4 + nb   [co-permuted for
//   vectorized epilogue stores; conv stack is channel-permutation covariant]
__global__ __launch_bounds__(256)
void prep_all(const float* __restrict__ x, unsigned short* __restrict__ xcl,
              const float* __restrict__ w0, const float* __restrict__ wm,
              const float* __restrict__ wl, unsigned short* __restrict__ Wf,
              const float* b0, const float* g0, const float* be0,
              const float* m0, const float* v0,
              const float* bm, const float* gm, const float* bem,
              const float* mm, const float* vm,
              const float* bl, const float* gl, const float* bel,
              const float* ml, const float* vl,
              float* __restrict__ Af, float* __restrict__ Bf,
              unsigned int* __restrict__ zp)
{
    const int bid = blockIdx.x;
    const int t = threadIdx.x;
    if (bid < 1024) {
        // ---- prep_x: fp32 NCHW -> bf16 channel-last [n][h][w][c]
        __shared__ unsigned short t2[128 * 68];
        int n = bid >> 7, h = bid & 127;
        const float* xp = x + (size_t)n * 64 * 16384 + h * 128;
        for (int i = t; i < 8192; i += 256) {
            int ci = i >> 7, w = i & 127;
            t2[w * 68 + ci] = f2us(xp[(size_t)ci * 16384 + w]);
        }
        __syncthreads();
        unsigned short* op = xcl + ((size_t)(n * 16384 + h * 128)) * 64;
        for (int i = t; i < 1024; i += 256) {
            int w = i >> 3, c8 = i & 7;
            union { bf16x4 v[2]; uint4 q; } u;
            u.v[0] = *(bf16x4*)&t2[w * 68 + c8 * 8];
            u.v[1] = *(bf16x4*)&t2[w * 68 + c8 * 8 + 4];
            *(uint4*)(op + w * 64 + c8 * 8) = u.q;
        }
    } else if (bid < 2032) {
        // ---- prep_wf
        int idx = (bid - 1024) * 256 + t;
        int l = idx / 36864, r = idx - l * 36864;
        int tp = r >> 12, r2 = r & 4095;
        int hh = r2 >> 11, nb = (r2 >> 9) & 3, ln = (r2 >> 3) & 63, j = r2 & 7;
        int ci = hh * 32 + (ln >> 4) * 8 + j;
        int co = (ln & 15) * 4 + nb;          // permuted co
        float val = 0.f;
        if (l < 6) {
            const float* src = (l == 0) ? w0 : (wm + (size_t)(l - 1) * 36864);
            val = src[(co * 64 + ci) * 9 + tp];
        } else if (co < 36) {
            val = wl[(co * 64 + ci) * 9 + tp];
        }
        Wf[idx] = f2us(val);
    } else {
        // ---- prep_ab + zero page
        int idx = (bid - 2032) * 256 + t;
        if (bid == 2033 && t >= 192) zp[t - 192] = 0u;   // 256 B zero page
        if (idx < 448) {
            int l = idx >> 6, c = idx & 63;
            float b, g, be, m, v;
            bool zero = false;
            if (l == 0) {
                b = b0[c]; g = g0[c]; be = be0[c]; m = m0[c]; v = v0[c];
            } else if (l < 6) {
                int o = (l - 1) * 64 + c;
                b = bm[o]; g = gm[o]; be = bem[o]; m = mm[o]; v = vm[o];
            } else if (c < 36) {
                b = bl[c]; g = gl[c]; be = bel[c]; m = ml[c]; v = vl[c];
            } else zero = true;
            if (zero) { Af[idx] = 0.f; Bf[idx] = 0.f; }
            else {
                float s = g / sqrtf(v + 1e-5f);
                Af[idx] = s;
                Bf[idx] = (b - m) * s + be;
            }
        }
    }
}

// ---------------- conv 3x3 + BN + tanh via MFMA implicit GEMM -------------------
// grid (4,8,8) = (w/32, h/16, n), block 512 = 8 waves, 1 block/CU (LDS 152064 B).
// Tile: 32w x 16h output px; halo 34w x 18h, channel-last bf16, row stride 128 B.
// LDS tile: px p = ty*34+tx at [p*128, p*128+128); chunk j stored at j ^ (p&7)
// (XOR swizzle via pre-swizzled global source; read applies same XOR).
// OOB halo lanes DMA from a 256-B zero page (no LDS pre-zeroing needed).
// Weights (73728 B) staged once per block at LDS_W_OFF.
#define LDS_W_OFF 78336
__global__ __launch_bounds__(512, 2)
void conv_mfma(const unsigned short* __restrict__ src,
               const unsigned short* __restrict__ Wf,
               const float* __restrict__ A, const float* __restrict__ B,
               unsigned short* __restrict__ dst,
               const unsigned short* __restrict__ zp)
{
    __shared__ __align__(16) unsigned char smem[152064];   // 78336 tile + 73728 W
    const int n = blockIdx.z;
    const int h0 = blockIdx.y * 16, w0 = blockIdx.x * 32;
    const int t = threadIdx.x;
    const int ln = t & 63, wv = t >> 6;
    const int xln = ln & 15, qd = ln >> 4;
    const size_t ibase = (size_t)n * 16384 * 64;

    // stage input tile: 612 px * 8 chunks = 4896 chunks, 77 wave-insts
    const unsigned short* srcn = src + ibase;
    for (int i = wv; i < 77; i += 8) {
        int g = i * 64 + ln;
        int p = g >> 3, jj = g & 7;
        int ty = (p * 1928) >> 16;          // p/34, exact for p<612
        int tx = p - ty * 34;
        int gy = h0 + ty - 1, gx = w0 + tx - 1;
        int js = jj ^ (p & 7);              // inverse-swizzled source chunk
        const unsigned short* gsrc =
            (((unsigned)gy < 128u) & ((unsigned)gx < 128u))
                ? srcn + (ptrdiff_t)(gy * 128 + gx) * 64 + js * 8
                : zp;                        // zero page for halo OOB
        if (g < 4896) gload_lds16(gsrc, smem + (size_t)i * 1024);
    }
    // stage weights: 73728 B = 4608 chunks, 72 wave-insts, linear
    for (int i = wv; i < 72; i += 8) {
        const unsigned short* gsrc = Wf + ((size_t)(i * 64 + ln)) * 8;
        gload_lds16(gsrc, smem + LDS_W_OFF + (size_t)i * 1024);
    }
    __syncthreads();   // drains vmcnt(0): all DMA landed

    f32x4 acc[2][2][4];     // [rh][half][nb]
#pragma unroll
    for (int rh = 0; rh < 2; ++rh)
#pragma unroll
        for (int hf = 0; hf < 2; ++hf)
#pragma unroll
            for (int nb = 0; nb < 4; ++nb)
                acc[rh][hf][nb] = (f32x4){0.f, 0.f, 0.f, 0.f};

    const int rbase = wv * 2;
#pragma unroll
    for (int tp = 0; tp < 9; ++tp) {
        const int ky = tp / 3, kx = tp % 3;
        bf16x8 b[2][4];
#pragma unroll
        for (int hh = 0; hh < 2; ++hh)
#pragma unroll
            for (int nb = 0; nb < 4; ++nb)
                b[hh][nb] = *(const bf16x8*)(smem + LDS_W_OFF +
                    (((((tp * 2 + hh) * 4 + nb) * 64) + ln) << 4));
#pragma unroll
        for (int rh = 0; rh < 2; ++rh) {
#pragma unroll
            for (int hf = 0; hf < 2; ++hf) {
                const int p = (rbase + rh + ky) * 34 + hf * 16 + xln + kx;
                const int pb = p * 128, sw = (p & 7) << 4;
#pragma unroll
                for (int hh = 0; hh < 2; ++hh) {
                    bf16x8 a = *(const bf16x8*)(smem + pb +
                                                (((qd + 4 * hh) << 4) ^ sw));
#pragma unroll
                    for (int nb = 0; nb < 4; ++nb)
                        acc[rh][hf][nb] = __builtin_amdgcn_mfma_f32_16x16x32_bf16(
                            a, b[hh][nb], acc[rh][hf][nb], 0, 0, 0);
                }
            }
        }
    }

    // epilogue: BN + tanh -> bf16 channel-last; thread owns co = 4*xln..4*xln+3
    const float4 A4 = *(const float4*)&A[xln * 4];
    const float4 B4 = *(const float4*)&B[xln * 4];
#pragma unroll
    for (int rh = 0; rh < 2; ++rh) {
        const int gy = h0 + rbase + rh;
        unsigned short* dp = dst + ibase + (size_t)(gy * 128) * 64 + xln * 4;
#pragma unroll
        for (int hf = 0; hf < 2; ++hf) {
#pragma unroll
            for (int r = 0; r < 4; ++r) {
                const int gx = w0 + hf * 16 + qd * 4 + r;
                ushort4 o;
                o.x = f2us(tanh_fast(fmaf(acc[rh][hf][0][r], A4.x, B4.x)));
                o.y = f2us(tanh_fast(fmaf(acc[rh][hf][1][r], A4.y, B4.y)));
                o.z = f2us(tanh_fast(fmaf(acc[rh][hf][2][r], A4.z, B4.z)));
                o.w = f2us(tanh_fast(fmaf(acc[rh][hf][3][r], A4.w, B4.w)));
                *(ushort4*)(dp + (size_t)gx * 64) = o;
            }
        }
    }
}

// ---------------- dynamic conv: coef = h7·bases; out = coef · patches(x) -------
// grid (4,16,8), block 256 = 8x32 px. h7 is bf16 channel-last (64-stride, 36 used).
__global__ __launch_bounds__(256)
void dyn_conv(const float* __restrict__ x, const unsigned short* __restrict__ h7,
              const float* __restrict__ bases, float* __restrict__ out)
{
    __shared__ float tile[32 * 10 * 34];
    const int n = blockIdx.z;
    const int h0 = blockIdx.y * 8, w0 = blockIdx.x * 32;
    const float* xp = x + (size_t)n * 64 * 16384;
    const int t = threadIdx.x;
    const int tw = t & 31, th = t >> 5;
    const int h = h0 + th, w = w0 + tw;

    float bs[54];
#pragma unroll
    for (int i = 0; i < 54; ++i) bs[i] = bases[i];    // [k][l], block-uniform

    // load 36 bf16 features (contiguous) via 5 x uint4
    union { uint4 q[5]; unsigned short s[40]; } hv;
    const unsigned short* hp = h7 + (size_t)(n * 16384 + h * 128 + w) * 64;
#pragma unroll
    for (int i = 0; i < 5; ++i) hv.q[i] = ((const uint4*)hp)[i];

    float coef[54];   // [m][l]
#pragma unroll
    for (int i = 0; i < 54; ++i) coef[i] = 0.f;
#pragma unroll
    for (int m = 0; m < 6; ++m)
#pragma unroll
        for (int k = 0; k < 6; ++k) {
            float f = us2f(hv.s[m * 6 + k]);
#pragma unroll
            for (int l = 0; l < 9; ++l)
                coef[m * 9 + l] = fmaf(f, bs[k * 9 + l], coef[m * 9 + l]);
        }

    float* op = out + (size_t)n * 384 * 16384 + h * 128 + w;

    for (int half = 0; half < 2; ++half) {
        if (half) __syncthreads();
        for (int idx = t; idx < 32 * 340; idx += 256) {
            int ci = idx / 340, r = idx % 340, y = r / 34, xw = r % 34;
            int gy = h0 + y - 1, gx = w0 + xw - 1;
            float v = 0.f;
            if ((unsigned)gy < 128u && (unsigned)gx < 128u)
                v = xp[(size_t)(half * 32 + ci) * 16384 + gy * 128 + gx];
            tile[idx] = v;
        }
        __syncthreads();

#pragma unroll 1
        for (int c = 0; c < 32; ++c) {
            float xv[9];
#pragma unroll
            for (int ky = 0; ky < 3; ++ky)
#pragma unroll
                for (int kx = 0; kx < 3; ++kx)
                    xv[ky * 3 + kx] = tile[c * 340 + (th + ky) * 34 + (tw + kx)];
            int cg = half * 32 + c;
#pragma unroll
            for (int m = 0; m < 6; ++m) {
                float s = 0.f;
#pragma unroll
                for (int l = 0; l < 9; ++l) s = fmaf(coef[m * 9 + l], xv[l], s);
                op[(size_t)(cg * 6 + m) * 16384] = s;
            }
        }
    }
}

// ---------------- launch -------------------------------------------------------
extern "C" void kernel_launch(void* const* d_in, const int* in_sizes, int n_in,
                              void* d_out, int out_size, void* d_ws, size_t ws_size,
                              hipStream_t stream)
{
    const float* x   = (const float*)d_in[0];
    const float* w0  = (const float*)d_in[1];
    const float* b0  = (const float*)d_in[2];
    const float* g0  = (const float*)d_in[3];
    const float* be0 = (const float*)d_in[4];
    const float* m0  = (const float*)d_in[5];
    const float* v0  = (const float*)d_in[6];
    const float* wm  = (const float*)d_in[7];
    const float* bm  = (const float*)d_in[8];
    const float* gm  = (const float*)d_in[9];
    const float* bem = (const float*)d_in[10];
    const float* mm  = (const float*)d_in[11];
    const float* vm  = (const float*)d_in[12];
    const float* wl  = (const float*)d_in[13];
    const float* bl  = (const float*)d_in[14];
    const float* gl  = (const float*)d_in[15];
    const float* bel = (const float*)d_in[16];
    const float* ml  = (const float*)d_in[17];
    const float* vl  = (const float*)d_in[18];
    const float* bas = (const float*)d_in[19];

    unsigned short* Wfb = (unsigned short*)d_ws;                    // 516096 B
    float* Af  = (float*)((char*)d_ws + 524288);                    // 448 floats
    float* Bf  = Af + 448;
    unsigned int* zp = (unsigned int*)((char*)d_ws + (1 << 20));    // 256 B zeros
    unsigned short* xcl  = (unsigned short*)((char*)d_ws + (size_t)(2  << 20));
    unsigned short* bufA = (unsigned short*)((char*)d_ws + (size_t)(2  << 20) + 16777216);
    unsigned short* bufB = (unsigned short*)((char*)d_ws + (size_t)(2  << 20) + 2 * 16777216);

    prep_all<<<2034, 256, 0, stream>>>(x, xcl, w0, wm, wl, Wfb,
                                       b0, g0, be0, m0, v0,
                                       bm, gm, bem, mm, vm,
                                       bl, gl, bel, ml, vl, Af, Bf, zp);

    dim3 cg(4, 8, 8);
    const unsigned short* zps = (const unsigned short*)zp;
    conv_mfma<<<cg, 512, 0, stream>>>(xcl,  Wfb + 0 * 36864, Af + 0,   Bf + 0,   bufA, zps);
    conv_mfma<<<cg, 512, 0, stream>>>(bufA, Wfb + 1 * 36864, Af + 64,  Bf + 64,  bufB, zps);
    conv_mfma<<<cg, 512, 0, stream>>>(bufB, Wfb + 2 * 36864, Af + 128, Bf + 128, bufA, zps);
    conv_mfma<<<cg, 512, 0, stream>>>(bufA, Wfb + 3 * 36864, Af + 192, Bf + 192, bufB, zps);
    conv_mfma<<<cg, 512, 0, stream>>>(bufB, Wfb + 4 * 36864, Af + 256, Bf + 256, bufA, zps);
    conv_mfma<<<cg, 512, 0, stream>>>(bufA, Wfb + 5 * 36864, Af + 320, Bf + 320, bufB, zps);
    conv_mfma<<<cg, 512, 0, stream>>>(bufB, Wfb + 6 * 36864, Af + 384, Bf + 384, bufA, zps);

    dim3 dg(4, 16, 8);
    dyn_conv<<<dg, 256, 0, stream>>>(x, bufA, bas, (float*)d_out);
}